// Round 10
// baseline (122.531 us; speedup 1.0000x reference)
//
#include <hip/hip_runtime.h>
#include <hip/hip_bf16.h>
#include <stdint.h>

// ============================================================================
// Fused causal self-attention block: QKV projection + flash attention.
// bf16 MFMA. No-max softmax (scores bounded; log2e folded into Q scale).
// k_attn v9: K staged via global_load_lds (dbuf, XOR-swizzled, batched
// ds_read_b128); V read DIRECT from L2-resident Vt into registers, staggered
// per 32-kv half (loads hidden under exp+P-store). LDS 41,984B -> 3 blocks/CU
// (3 waves/SIMD). Waves own 32 q-rows; 4-wave blocks cover 128 q-rows;
// kv-chunks <=8 tiles, 576 blocks, heavy-first, XCD-bijective.
// Swapped QK^T (S^T) + transposed PV (O^T); P per-wave LDS stride-36.
// ============================================================================

typedef __bf16 bf16x8 __attribute__((ext_vector_type(8)));
typedef float  f32x4  __attribute__((ext_vector_type(4)));
typedef unsigned int u32x4 __attribute__((ext_vector_type(4)));
typedef unsigned int u32x2 __attribute__((ext_vector_type(2)));

using bf16 = __hip_bfloat16;

#define AS1 __attribute__((address_space(1)))
#define AS3 __attribute__((address_space(3)))

__device__ __forceinline__ void gl_lds16(const void* g, void* l) {
  __builtin_amdgcn_global_load_lds((AS1 uint32_t*)g, (AS3 uint32_t*)l, 16, 0, 0);
}

// ---------------------------------------------------------------------------
// 1) W [1024][128] fp32 -> Wt[z][128][1024] bf16 (transpose via LDS tile)
// ---------------------------------------------------------------------------
__global__ __launch_bounds__(256) void k_wt(const float* __restrict__ Wq,
                                            const float* __restrict__ Wk,
                                            const float* __restrict__ Wv,
                                            bf16* __restrict__ Wt) {
  __shared__ bf16 t[64][72];
  const float* W = blockIdx.z == 0 ? Wq : (blockIdx.z == 1 ? Wk : Wv);
  int k0 = blockIdx.x * 64, n0 = blockIdx.y * 64;
  int tid = threadIdx.x;
  int r = tid >> 4, c4 = (tid & 15) * 4;
#pragma unroll
  for (int s = 0; s < 4; ++s) {
    int rr = r + s * 16;
    float4 v = *(const float4*)(W + (size_t)(k0 + rr) * 128 + n0 + c4);
    t[rr][c4 + 0] = __float2bfloat16(v.x);
    t[rr][c4 + 1] = __float2bfloat16(v.y);
    t[rr][c4 + 2] = __float2bfloat16(v.z);
    t[rr][c4 + 3] = __float2bfloat16(v.w);
  }
  __syncthreads();
  bf16* out = Wt + (size_t)blockIdx.z * 128 * 1024;
#pragma unroll
  for (int s = 0; s < 4; ++s) {
    int rn = r + s * 16;
    union { bf16 h[4]; u32x2 v; } u;
    u.h[0] = t[c4 + 0][rn]; u.h[1] = t[c4 + 1][rn];
    u.h[2] = t[c4 + 2][rn]; u.h[3] = t[c4 + 3][rn];
    *(u32x2*)(out + (size_t)(n0 + rn) * 1024 + k0 + c4) = u.v;
  }
}

// ---------------------------------------------------------------------------
// 2) fused QKV projection + in-kernel V transpose (unchanged, proven)
// ---------------------------------------------------------------------------
__global__ __launch_bounds__(512) void k_qkv(const float* __restrict__ X,
                                             const bf16* __restrict__ Wt,
                                             const float* __restrict__ bq,
                                             const float* __restrict__ bk,
                                             const float* __restrict__ bv,
                                             bf16* __restrict__ Qo,
                                             bf16* __restrict__ Ko,
                                             bf16* __restrict__ Vt) {
  __shared__ __align__(16) char smem[65536];
  float* Xs = (float*)smem;                  // [2][64*32] f32, 16 KB
  bf16* Ws = (bf16*)(smem + 16384);          // [2][3*128*32] bf16, 48 KB
  bf16* Vs = (bf16*)smem;                    // epilogue: [64][136], 17.4 KB

  const int m0 = blockIdx.x * 64;
  const int tid = threadIdx.x;
  const int lane = tid & 63;
  const int li = lane & 15, g = lane >> 4;
  const int wid = tid >> 6;
  const int wm = wid >> 2, wn = wid & 3;

  const int xr = tid >> 3;
  const int xc32 = (tid & 7) >> 1;
  const int xhf = tid & 1;
  const int wr = tid >> 2;
  const int wc = tid & 3;

  f32x4 acc[3][2][2] = {};

  {
    gl_lds16(X + (size_t)(m0 + xr) * 1024 + (xc32 ^ (xr & 3)) * 8 + xhf * 4,
             Xs + tid * 4);
#pragma unroll
    for (int z = 0; z < 3; ++z)
      gl_lds16(Wt + (size_t)z * 131072 + (size_t)wr * 1024 + (wc ^ (wr & 3)) * 8,
               Ws + z * 4096 + tid * 8);
  }
  int cur = 0;
  for (int kt = 0; kt < 32; ++kt) {
    __syncthreads();
    if (kt < 31) {
      const int k0 = (kt + 1) * 32;
      gl_lds16(X + (size_t)(m0 + xr) * 1024 + k0 + (xc32 ^ (xr & 3)) * 8 + xhf * 4,
               Xs + (cur ^ 1) * 2048 + tid * 4);
#pragma unroll
      for (int z = 0; z < 3; ++z)
        gl_lds16(Wt + (size_t)z * 131072 + (size_t)wr * 1024 + k0 + (wc ^ (wr & 3)) * 8,
                 Ws + (cur ^ 1) * 12288 + z * 4096 + tid * 8);
    }
    bf16x8 af[2];
#pragma unroll
    for (int mf = 0; mf < 2; ++mf) {
      int r = wm * 32 + mf * 16 + li;
      const float* xp = Xs + cur * 2048 + r * 32 + ((g ^ (r & 3)) * 8);
      f32x4 x0 = *(const f32x4*)xp;
      f32x4 x1 = *(const f32x4*)(xp + 4);
      union { bf16 h[8]; bf16x8 v; } u;
      u.h[0] = __float2bfloat16(x0[0]); u.h[1] = __float2bfloat16(x0[1]);
      u.h[2] = __float2bfloat16(x0[2]); u.h[3] = __float2bfloat16(x0[3]);
      u.h[4] = __float2bfloat16(x1[0]); u.h[5] = __float2bfloat16(x1[1]);
      u.h[6] = __float2bfloat16(x1[2]); u.h[7] = __float2bfloat16(x1[3]);
      af[mf] = u.v;
    }
#pragma unroll
    for (int z = 0; z < 3; ++z) {
#pragma unroll
      for (int nf = 0; nf < 2; ++nf) {
        int r = wn * 32 + nf * 16 + li;
        bf16x8 bfrag =
            *(const bf16x8*)(Ws + cur * 12288 + z * 4096 + r * 32 + ((g ^ (r & 3)) * 8));
#pragma unroll
        for (int mf = 0; mf < 2; ++mf)
          acc[z][mf][nf] = __builtin_amdgcn_mfma_f32_16x16x32_bf16(
              af[mf], bfrag, acc[z][mf][nf], 0, 0, 0);
      }
    }
    cur ^= 1;
  }

#pragma unroll
  for (int z = 0; z < 2; ++z) {
    const float* bias = z == 0 ? bq : bk;
    bf16* Out = z == 0 ? Qo : Ko;
    const float scale = z == 0 ? 0.12752404368678202f : 1.0f;
#pragma unroll
    for (int nf = 0; nf < 2; ++nf) {
      int col = wn * 32 + nf * 16 + li;
      float bb = bias[col];
#pragma unroll
      for (int mf = 0; mf < 2; ++mf)
#pragma unroll
        for (int j = 0; j < 4; ++j) {
          int row = m0 + wm * 32 + mf * 16 + g * 4 + j;
          Out[(size_t)row * 128 + col] =
              __float2bfloat16((acc[z][mf][nf][j] + bb) * scale);
        }
    }
  }

  __syncthreads();
#pragma unroll
  for (int nf = 0; nf < 2; ++nf) {
    int col = wn * 32 + nf * 16 + li;
    float bb = bv[col];
#pragma unroll
    for (int mf = 0; mf < 2; ++mf)
#pragma unroll
      for (int j = 0; j < 4; ++j) {
        int row = wm * 32 + mf * 16 + g * 4 + j;
        Vs[row * 136 + col] = __float2bfloat16(acc[2][mf][nf][j] + bb);
      }
  }
  __syncthreads();
  const int b = m0 >> 12;
  const int s_off = m0 & 4095;
#pragma unroll
  for (int t2 = 0; t2 < 2; ++t2) {
    int idx = tid + 512 * t2;
    int dv = idx & 127;
    int sg = idx >> 7;
    union { bf16 h[8]; u32x4 v; } u;
#pragma unroll
    for (int si = 0; si < 8; ++si) u.h[si] = Vs[(sg * 8 + si) * 136 + dv];
    *(u32x4*)(Vt + (size_t)(b * 128 + dv) * 4096 + s_off + sg * 8) = u.v;
  }
}

// ---------------------------------------------------------------------------
// 3) causal flash attention v9. 256 thr = 4 waves x 32 q-rows (q-tile 128).
//    kv tiles = 2(qt+1), chunks <=8, blocks/batch = 144, grid 576.
//    K dbuf LDS (swizzled); V direct-from-global per-half reg prefetch.
//    P per-wave LDS stride-36. LDS 41,984B -> 3 blocks/CU.
// ---------------------------------------------------------------------------
__global__ __launch_bounds__(256, 3) void k_attn(const bf16* __restrict__ Qb,
                                                 const bf16* __restrict__ Kb,
                                                 const bf16* __restrict__ Vt,
                                                 bf16* __restrict__ o_part,
                                                 float* __restrict__ l_part) {
  __shared__ __align__(16) bf16 Kls[2][64 * 128];  // 32 KB [kv][d] swizzled
  __shared__ __align__(16) bf16 Pls[4][32 * 36];   // 9.2 KB per-wave P halves

  const int bid = blockIdx.x;
  const int xcd = bid & 7;
  const int slot = xcd * 72 + (bid >> 3);     // bijective (576 = 8*72)
  const int b = slot / 144;
  const int s = 143 - (slot - b * 144);       // heavy-first work index
  const int widx = b * 144 + s;               // partial-buffer index (k_comb's)
  int qt = 0;
#pragma unroll
  for (int q2 = 1; q2 < 32; ++q2) {
    int M = q2 >> 2;
    if ((M + 1) * (2 * M + (q2 & 3)) <= s) qt = q2;
  }
  const int Mq = qt >> 2;
  const int chunk = s - (Mq + 1) * (2 * Mq + (qt & 3));
  const int ntiles = 2 * qt + 2;
  const int nch = (qt + 4) >> 2;
  const int clen = ntiles / nch;
  const int crem = ntiles - clen * nch;
  const int kt0 = chunk * clen + min(chunk, crem);
  const int kt1 = kt0 + clen + (chunk < crem ? 1 : 0) - 1;

  const int tid = threadIdx.x;
  const int lane = tid & 63;
  const int li = lane & 15, g = lane >> 4;
  const int w = tid >> 6;

  // Q fragments: 32 q-rows/wave via 2 B-frags (q = qt*128 + w*32 + qb*16 + li)
  bf16x8 qf[2][4];
#pragma unroll
  for (int qb = 0; qb < 2; ++qb)
#pragma unroll
    for (int ks = 0; ks < 4; ++ks)
      qf[qb][ks] = *(const bf16x8*)(Qb +
          (size_t)(b * 4096 + qt * 128 + w * 32 + qb * 16 + li) * 128 +
          ks * 32 + g * 8);

  f32x4 o[2][8] = {};
  f32x4 lacc[2] = {};
  bf16x8 ones;
#pragma unroll
  for (int e = 0; e < 8; ++e) ones[e] = (__bf16)1.0f;

  bf16* P = &Pls[w][0];
  const bf16* Vtb = Vt + (size_t)b * 128 * 4096;

  // prologue: stage K tile kt0 -> buf 0 (4 gl_lds16/thread)
  {
    const int kv0 = kt0 * 64;
#pragma unroll
    for (int ii = 0; ii < 4; ++ii) {
      int c = tid + 256 * ii;
      int r = c >> 4, cc = c & 15;
      gl_lds16(Kb + (size_t)(b * 4096 + kv0 + r) * 128 + (cc ^ (r & 7)) * 8,
               &Kls[0][c * 8]);
    }
  }
  int cur = 0;
  for (int kt = kt0; kt <= kt1; ++kt) {
    __syncthreads();  // buf[cur] staged; all waves done with buf[cur^1]
    if (kt < kt1) {
      const int kv0n = (kt + 1) * 64;
#pragma unroll
      for (int ii = 0; ii < 4; ++ii) {
        int c = tid + 256 * ii;
        int r = c >> 4, cc = c & 15;
        gl_lds16(Kb + (size_t)(b * 4096 + kv0n + r) * 128 + (cc ^ (r & 7)) * 8,
                 &Kls[cur ^ 1][c * 8]);
      }
    }
    const bf16* Kl = &Kls[cur][0];
    const int kv0 = kt * 64;

    // S^T = K Q^T : st[qb][nf][j] = S^T[kv=nf*16+g*4+j][q=w*32+qb*16+li]
    f32x4 st[2][4] = {};
#pragma unroll
    for (int ks = 0; ks < 4; ++ks) {
      bf16x8 kf[4];
#pragma unroll
      for (int nf = 0; nf < 4; ++nf) {
        int r = nf * 16 + li;
        int ch = (ks * 4 + g) ^ (r & 7);
        kf[nf] = *(const bf16x8*)(Kl + r * 128 + ch * 8);
      }
#pragma unroll
      for (int nf = 0; nf < 4; ++nf)
#pragma unroll
        for (int qb = 0; qb < 2; ++qb)
          st[qb][nf] = __builtin_amdgcn_mfma_f32_16x16x32_bf16(
              kf[nf], qf[qb][ks], st[qb][nf], 0, 0, 0);
    }

    if (kt >= 2 * qt) {  // diagonal tiles: causal mask (kv > q)
      const int dk = kv0 - qt * 128;
#pragma unroll
      for (int qb = 0; qb < 2; ++qb) {
        const int qloc = w * 32 + qb * 16 + li;
#pragma unroll
        for (int nf = 0; nf < 4; ++nf)
#pragma unroll
          for (int j = 0; j < 4; ++j)
            if (dk + nf * 16 + g * 4 + j > qloc) st[qb][nf][j] = -1e30f;
      }
    }

    // kv-halved softmax+PV: half h covers kv [h*32, h*32+32)
#pragma unroll
    for (int h = 0; h < 2; ++h) {
      // V prefetch for this half (loads hide under exp + P store)
      bf16x8 vf[8];
#pragma unroll
      for (int dvf = 0; dvf < 8; ++dvf)
        vf[dvf] = *(const bf16x8*)(Vtb +
            (size_t)(dvf * 16 + li) * 4096 + kv0 + h * 32 + g * 8);
      // P = exp2(S) -> b64 stores, P[q'=qb*16+li][c = nfh*16+g*4], stride 36
#pragma unroll
      for (int qb = 0; qb < 2; ++qb)
#pragma unroll
        for (int nfh = 0; nfh < 2; ++nfh) {
          const f32x4 sv = st[qb][h * 2 + nfh];
          union { bf16 h4[4]; u32x2 v; } u;
#pragma unroll
          for (int j = 0; j < 4; ++j)
            u.h4[j] = __float2bfloat16(exp2f(sv[j]));
          *(u32x2*)(P + (qb * 16 + li) * 36 + nfh * 16 + g * 4) = u.v;
        }
      // pa: B-frag P^T[k=kv half][n=q], b128 read
      bf16x8 pa[2];
#pragma unroll
      for (int qb = 0; qb < 2; ++qb)
        pa[qb] = *(const bf16x8*)(P + (qb * 16 + li) * 36 + g * 8);
      // O^T += V^T P^T ; l via ones-MFMA
#pragma unroll
      for (int dvf = 0; dvf < 8; ++dvf) {
#pragma unroll
        for (int qb = 0; qb < 2; ++qb)
          o[qb][dvf] = __builtin_amdgcn_mfma_f32_16x16x32_bf16(
              vf[dvf], pa[qb], o[qb][dvf], 0, 0, 0);
      }
#pragma unroll
      for (int qb = 0; qb < 2; ++qb)
        lacc[qb] = __builtin_amdgcn_mfma_f32_16x16x32_bf16(
            ones, pa[qb], lacc[qb], 0, 0, 0);
    }
    cur ^= 1;
  }

  // partials at WORK index widx: O^T lane layout -> b64 stores
  bf16* op = o_part + (size_t)widx * (128 * 128);
  float* lp = l_part + widx * 128;
#pragma unroll
  for (int qb = 0; qb < 2; ++qb) {
    const int qloc = w * 32 + qb * 16 + li;
    if (g == 0) lp[qloc] = lacc[qb][0];
#pragma unroll
    for (int dvf = 0; dvf < 8; ++dvf) {
      union { bf16 h4[4]; u32x2 v; } u;
#pragma unroll
      for (int j = 0; j < 4; ++j) u.h4[j] = __float2bfloat16(o[qb][dvf][j]);
      *(u32x2*)(op + (size_t)qloc * 128 + dvf * 16 + g * 4) = u.v;
    }
  }
}

// ---------------------------------------------------------------------------
// 4) combine chunk partials: out[row] = sum_c O_c[row] / sum_c l_c[row]
//    q-tile 128: qt = rb>>7; base(qt) = (M+1)(2M + (qt&3)), M=qt>>2;
//    n = (qt+4)>>2 (<=8). partial strides: O 16384, l 128.
// ---------------------------------------------------------------------------
__global__ __launch_bounds__(256) void k_comb(const bf16* __restrict__ op,
                                              const float* __restrict__ lp,
                                              float* __restrict__ out) {
  int i = blockIdx.x * 256 + threadIdx.x;  // 4-col group index, < 524288
  int row = i >> 5;
  int col4 = (i & 31) * 4;
  int b = row >> 12;
  int rb = row & 4095;
  int qt = rb >> 7;
  int lr = rb & 127;
  int M = qt >> 2;
  int base = b * 144 + (M + 1) * (2 * M + (qt & 3));
  int n = (qt + 4) >> 2;
  float l = 0.0f;
  float acc0 = 0, acc1 = 0, acc2 = 0, acc3 = 0;
  for (int c = 0; c < n; ++c) {
    l += lp[(base + c) * 128 + lr];
    union { bf16 h[4]; u32x2 v; } u;
    u.v = *(const u32x2*)(op + (size_t)(base + c) * 16384 + lr * 128 + col4);
    acc0 += __bfloat162float(u.h[0]);
    acc1 += __bfloat162float(u.h[1]);
    acc2 += __bfloat162float(u.h[2]);
    acc3 += __bfloat162float(u.h[3]);
  }
  float linv = 1.0f / l;
  float4 rv;
  rv.x = acc0 * linv; rv.y = acc1 * linv; rv.z = acc2 * linv; rv.w = acc3 * linv;
  ((float4*)out)[i] = rv;
}

// ---------------------------------------------------------------------------
extern "C" void kernel_launch(void* const* d_in, const int* in_sizes, int n_in,
                              void* d_out, int out_size, void* d_ws, size_t ws_size,
                              hipStream_t stream) {
  const float* X  = (const float*)d_in[0];
  const float* Wq = (const float*)d_in[1];
  const float* bq = (const float*)d_in[2];
  const float* Wk = (const float*)d_in[3];
  const float* bk = (const float*)d_in[4];
  const float* Wv = (const float*)d_in[5];
  const float* bv = (const float*)d_in[6];
  float* out = (float*)d_out;

  char* ws = (char*)d_ws;
  // layout (bytes) — fully disjoint, extent 32,538,624 (proven size)
  bf16* Wt  = (bf16*)(ws + 0);              //    786,432
  bf16* Qb  = (bf16*)(ws + 786432);         //  4,194,304
  bf16* Kb  = (bf16*)(ws + 4980736);        //  4,194,304
  bf16* Vt  = (bf16*)(ws + 9175040);        //  4,194,304
  bf16* o_part = (bf16*)(ws + 13369344);    // 18,874,368 (576*128*128*2)
  float* l_part = (float*)(ws + 32243712);  //    294,912

  k_wt<<<dim3(16, 2, 3), dim3(256), 0, stream>>>(Wq, Wk, Wv, Wt);
  k_qkv<<<dim3(256), dim3(512), 0, stream>>>(X, Wt, bq, bk, bv, Qb, Kb, Vt);
  k_attn<<<dim3(576), dim3(256), 0, stream>>>(Qb, Kb, Vt, o_part, l_part);
  k_comb<<<dim3(2048), dim3(256), 0, stream>>>(o_part, l_part, out);
}

// Round 11
// 97.735 us; speedup vs baseline: 1.2537x; 1.2537x over previous
//
#include <hip/hip_runtime.h>
#include <hip/hip_bf16.h>
#include <stdint.h>

// ============================================================================
// Fused causal self-attention block: QKV projection + flash attention.
// bf16 MFMA. No-max softmax (scores bounded; log2e folded into Q scale).
// k_attn v10: K AND V single-buffered in LDS (global_load_lds, XOR-swizzled,
// batched ds_read_b128), 2-barrier-per-tile pattern; LDS 41,984B -> 3
// blocks/CU (12 waves/CU TLP hides exposed staging). Waves own 32 q-rows;
// 4-wave blocks cover 128 q-rows; kv-chunks <=8 tiles, 576 blocks,
// heavy-first, XCD-bijective. Swapped QK^T (S^T) + transposed PV (O^T);
// P per-wave LDS stride-36, kv-halved.
// ============================================================================

typedef __bf16 bf16x8 __attribute__((ext_vector_type(8)));
typedef float  f32x4  __attribute__((ext_vector_type(4)));
typedef unsigned int u32x4 __attribute__((ext_vector_type(4)));
typedef unsigned int u32x2 __attribute__((ext_vector_type(2)));

using bf16 = __hip_bfloat16;

#define AS1 __attribute__((address_space(1)))
#define AS3 __attribute__((address_space(3)))

__device__ __forceinline__ void gl_lds16(const void* g, void* l) {
  __builtin_amdgcn_global_load_lds((AS1 uint32_t*)g, (AS3 uint32_t*)l, 16, 0, 0);
}

// ---------------------------------------------------------------------------
// 1) W [1024][128] fp32 -> Wt[z][128][1024] bf16 (transpose via LDS tile)
// ---------------------------------------------------------------------------
__global__ __launch_bounds__(256) void k_wt(const float* __restrict__ Wq,
                                            const float* __restrict__ Wk,
                                            const float* __restrict__ Wv,
                                            bf16* __restrict__ Wt) {
  __shared__ bf16 t[64][72];
  const float* W = blockIdx.z == 0 ? Wq : (blockIdx.z == 1 ? Wk : Wv);
  int k0 = blockIdx.x * 64, n0 = blockIdx.y * 64;
  int tid = threadIdx.x;
  int r = tid >> 4, c4 = (tid & 15) * 4;
#pragma unroll
  for (int s = 0; s < 4; ++s) {
    int rr = r + s * 16;
    float4 v = *(const float4*)(W + (size_t)(k0 + rr) * 128 + n0 + c4);
    t[rr][c4 + 0] = __float2bfloat16(v.x);
    t[rr][c4 + 1] = __float2bfloat16(v.y);
    t[rr][c4 + 2] = __float2bfloat16(v.z);
    t[rr][c4 + 3] = __float2bfloat16(v.w);
  }
  __syncthreads();
  bf16* out = Wt + (size_t)blockIdx.z * 128 * 1024;
#pragma unroll
  for (int s = 0; s < 4; ++s) {
    int rn = r + s * 16;
    union { bf16 h[4]; u32x2 v; } u;
    u.h[0] = t[c4 + 0][rn]; u.h[1] = t[c4 + 1][rn];
    u.h[2] = t[c4 + 2][rn]; u.h[3] = t[c4 + 3][rn];
    *(u32x2*)(out + (size_t)(n0 + rn) * 1024 + k0 + c4) = u.v;
  }
}

// ---------------------------------------------------------------------------
// 2) fused QKV projection + in-kernel V transpose (unchanged, proven)
// ---------------------------------------------------------------------------
__global__ __launch_bounds__(512) void k_qkv(const float* __restrict__ X,
                                             const bf16* __restrict__ Wt,
                                             const float* __restrict__ bq,
                                             const float* __restrict__ bk,
                                             const float* __restrict__ bv,
                                             bf16* __restrict__ Qo,
                                             bf16* __restrict__ Ko,
                                             bf16* __restrict__ Vt) {
  __shared__ __align__(16) char smem[65536];
  float* Xs = (float*)smem;                  // [2][64*32] f32, 16 KB
  bf16* Ws = (bf16*)(smem + 16384);          // [2][3*128*32] bf16, 48 KB
  bf16* Vs = (bf16*)smem;                    // epilogue: [64][136], 17.4 KB

  const int m0 = blockIdx.x * 64;
  const int tid = threadIdx.x;
  const int lane = tid & 63;
  const int li = lane & 15, g = lane >> 4;
  const int wid = tid >> 6;
  const int wm = wid >> 2, wn = wid & 3;

  const int xr = tid >> 3;
  const int xc32 = (tid & 7) >> 1;
  const int xhf = tid & 1;
  const int wr = tid >> 2;
  const int wc = tid & 3;

  f32x4 acc[3][2][2] = {};

  {
    gl_lds16(X + (size_t)(m0 + xr) * 1024 + (xc32 ^ (xr & 3)) * 8 + xhf * 4,
             Xs + tid * 4);
#pragma unroll
    for (int z = 0; z < 3; ++z)
      gl_lds16(Wt + (size_t)z * 131072 + (size_t)wr * 1024 + (wc ^ (wr & 3)) * 8,
               Ws + z * 4096 + tid * 8);
  }
  int cur = 0;
  for (int kt = 0; kt < 32; ++kt) {
    __syncthreads();
    if (kt < 31) {
      const int k0 = (kt + 1) * 32;
      gl_lds16(X + (size_t)(m0 + xr) * 1024 + k0 + (xc32 ^ (xr & 3)) * 8 + xhf * 4,
               Xs + (cur ^ 1) * 2048 + tid * 4);
#pragma unroll
      for (int z = 0; z < 3; ++z)
        gl_lds16(Wt + (size_t)z * 131072 + (size_t)wr * 1024 + k0 + (wc ^ (wr & 3)) * 8,
                 Ws + (cur ^ 1) * 12288 + z * 4096 + tid * 8);
    }
    bf16x8 af[2];
#pragma unroll
    for (int mf = 0; mf < 2; ++mf) {
      int r = wm * 32 + mf * 16 + li;
      const float* xp = Xs + cur * 2048 + r * 32 + ((g ^ (r & 3)) * 8);
      f32x4 x0 = *(const f32x4*)xp;
      f32x4 x1 = *(const f32x4*)(xp + 4);
      union { bf16 h[8]; bf16x8 v; } u;
      u.h[0] = __float2bfloat16(x0[0]); u.h[1] = __float2bfloat16(x0[1]);
      u.h[2] = __float2bfloat16(x0[2]); u.h[3] = __float2bfloat16(x0[3]);
      u.h[4] = __float2bfloat16(x1[0]); u.h[5] = __float2bfloat16(x1[1]);
      u.h[6] = __float2bfloat16(x1[2]); u.h[7] = __float2bfloat16(x1[3]);
      af[mf] = u.v;
    }
#pragma unroll
    for (int z = 0; z < 3; ++z) {
#pragma unroll
      for (int nf = 0; nf < 2; ++nf) {
        int r = wn * 32 + nf * 16 + li;
        bf16x8 bfrag =
            *(const bf16x8*)(Ws + cur * 12288 + z * 4096 + r * 32 + ((g ^ (r & 3)) * 8));
#pragma unroll
        for (int mf = 0; mf < 2; ++mf)
          acc[z][mf][nf] = __builtin_amdgcn_mfma_f32_16x16x32_bf16(
              af[mf], bfrag, acc[z][mf][nf], 0, 0, 0);
      }
    }
    cur ^= 1;
  }

#pragma unroll
  for (int z = 0; z < 2; ++z) {
    const float* bias = z == 0 ? bq : bk;
    bf16* Out = z == 0 ? Qo : Ko;
    const float scale = z == 0 ? 0.12752404368678202f : 1.0f;
#pragma unroll
    for (int nf = 0; nf < 2; ++nf) {
      int col = wn * 32 + nf * 16 + li;
      float bb = bias[col];
#pragma unroll
      for (int mf = 0; mf < 2; ++mf)
#pragma unroll
        for (int j = 0; j < 4; ++j) {
          int row = m0 + wm * 32 + mf * 16 + g * 4 + j;
          Out[(size_t)row * 128 + col] =
              __float2bfloat16((acc[z][mf][nf][j] + bb) * scale);
        }
    }
  }

  __syncthreads();
#pragma unroll
  for (int nf = 0; nf < 2; ++nf) {
    int col = wn * 32 + nf * 16 + li;
    float bb = bv[col];
#pragma unroll
    for (int mf = 0; mf < 2; ++mf)
#pragma unroll
      for (int j = 0; j < 4; ++j) {
        int row = wm * 32 + mf * 16 + g * 4 + j;
        Vs[row * 136 + col] = __float2bfloat16(acc[2][mf][nf][j] + bb);
      }
  }
  __syncthreads();
  const int b = m0 >> 12;
  const int s_off = m0 & 4095;
#pragma unroll
  for (int t2 = 0; t2 < 2; ++t2) {
    int idx = tid + 512 * t2;
    int dv = idx & 127;
    int sg = idx >> 7;
    union { bf16 h[8]; u32x4 v; } u;
#pragma unroll
    for (int si = 0; si < 8; ++si) u.h[si] = Vs[(sg * 8 + si) * 136 + dv];
    *(u32x4*)(Vt + (size_t)(b * 128 + dv) * 4096 + s_off + sg * 8) = u.v;
  }
}

// ---------------------------------------------------------------------------
// 3) causal flash attention v10. 256 thr = 4 waves x 32 q-rows (q-tile 128).
//    kv tiles = 2(qt+1), chunks <=8, blocks/batch = 144, grid 576.
//    K,V single-buffered LDS (swizzled), 2 barriers/tile; P stride-36.
//    LDS 41,984B -> 3 blocks/CU (12 waves/CU cross-block TLP).
// ---------------------------------------------------------------------------
__global__ __launch_bounds__(256, 3) void k_attn(const bf16* __restrict__ Qb,
                                                 const bf16* __restrict__ Kb,
                                                 const bf16* __restrict__ Vt,
                                                 bf16* __restrict__ o_part,
                                                 float* __restrict__ l_part) {
  __shared__ __align__(16) bf16 Kls[64 * 128];   // 16 KB [kv][d] swizzled
  __shared__ __align__(16) bf16 Vls[128 * 64];   // 16 KB [dv][kv] swizzled
  __shared__ __align__(16) bf16 Pls[4][32 * 36]; // 9.2 KB per-wave P halves

  const int bid = blockIdx.x;
  const int xcd = bid & 7;
  const int slot = xcd * 72 + (bid >> 3);     // bijective (576 = 8*72)
  const int b = slot / 144;
  const int s = 143 - (slot - b * 144);       // heavy-first work index
  const int widx = b * 144 + s;               // partial-buffer index (k_comb's)
  int qt = 0;
#pragma unroll
  for (int q2 = 1; q2 < 32; ++q2) {
    int M = q2 >> 2;
    if ((M + 1) * (2 * M + (q2 & 3)) <= s) qt = q2;
  }
  const int Mq = qt >> 2;
  const int chunk = s - (Mq + 1) * (2 * Mq + (qt & 3));
  const int ntiles = 2 * qt + 2;
  const int nch = (qt + 4) >> 2;
  const int clen = ntiles / nch;
  const int crem = ntiles - clen * nch;
  const int kt0 = chunk * clen + min(chunk, crem);
  const int kt1 = kt0 + clen + (chunk < crem ? 1 : 0) - 1;

  const int tid = threadIdx.x;
  const int lane = tid & 63;
  const int li = lane & 15, g = lane >> 4;
  const int w = tid >> 6;

  // Q fragments: 32 q-rows/wave via 2 B-frags (q = qt*128 + w*32 + qb*16 + li)
  bf16x8 qf[2][4];
#pragma unroll
  for (int qb = 0; qb < 2; ++qb)
#pragma unroll
    for (int ks = 0; ks < 4; ++ks)
      qf[qb][ks] = *(const bf16x8*)(Qb +
          (size_t)(b * 4096 + qt * 128 + w * 32 + qb * 16 + li) * 128 +
          ks * 32 + g * 8);

  f32x4 o[2][8] = {};
  f32x4 lacc[2] = {};
  bf16x8 ones;
#pragma unroll
  for (int e = 0; e < 8; ++e) ones[e] = (__bf16)1.0f;

  bf16* P = &Pls[w][0];
  const bf16* Vtb = Vt + (size_t)b * 128 * 4096;

  for (int kt = kt0; kt <= kt1; ++kt) {
    const int kv0 = kt * 64;
    // stage K+V tile kt (single buffer; 8 gl_lds16/thread)
#pragma unroll
    for (int ii = 0; ii < 4; ++ii) {
      int c = tid + 256 * ii;
      int r = c >> 4, cc = c & 15;
      gl_lds16(Kb + (size_t)(b * 4096 + kv0 + r) * 128 + (cc ^ (r & 7)) * 8,
               &Kls[c * 8]);
      int r2 = c >> 3, cc2 = c & 7;
      gl_lds16(Vtb + (size_t)r2 * 4096 + kv0 + (cc2 ^ (r2 & 7)) * 8,
               &Vls[c * 8]);
    }
    __syncthreads();  // staging drained -> tiles ready

    // S^T = K Q^T : st[qb][nf][j] = S^T[kv=nf*16+g*4+j][q=w*32+qb*16+li]
    f32x4 st[2][4] = {};
#pragma unroll
    for (int ks = 0; ks < 4; ++ks) {
      bf16x8 kf[4];
#pragma unroll
      for (int nf = 0; nf < 4; ++nf) {
        int r = nf * 16 + li;
        int ch = (ks * 4 + g) ^ (r & 7);
        kf[nf] = *(const bf16x8*)(Kls + r * 128 + ch * 8);
      }
#pragma unroll
      for (int nf = 0; nf < 4; ++nf)
#pragma unroll
        for (int qb = 0; qb < 2; ++qb)
          st[qb][nf] = __builtin_amdgcn_mfma_f32_16x16x32_bf16(
              kf[nf], qf[qb][ks], st[qb][nf], 0, 0, 0);
    }

    if (kt >= 2 * qt) {  // diagonal tiles: causal mask (kv > q)
      const int dk = kv0 - qt * 128;
#pragma unroll
      for (int qb = 0; qb < 2; ++qb) {
        const int qloc = w * 32 + qb * 16 + li;
#pragma unroll
        for (int nf = 0; nf < 4; ++nf)
#pragma unroll
          for (int j = 0; j < 4; ++j)
            if (dk + nf * 16 + g * 4 + j > qloc) st[qb][nf][j] = -1e30f;
      }
    }

    // kv-halved softmax+PV: half h covers kv [h*32, h*32+32)
#pragma unroll
    for (int h = 0; h < 2; ++h) {
      // P = exp2(S) -> b64 stores, P[q'=qb*16+li][c = nfh*16+g*4], stride 36
#pragma unroll
      for (int qb = 0; qb < 2; ++qb)
#pragma unroll
        for (int nfh = 0; nfh < 2; ++nfh) {
          const f32x4 sv = st[qb][h * 2 + nfh];
          union { bf16 h4[4]; u32x2 v; } u;
#pragma unroll
          for (int j = 0; j < 4; ++j)
            u.h4[j] = __float2bfloat16(exp2f(sv[j]));
          *(u32x2*)(P + (qb * 16 + li) * 36 + nfh * 16 + g * 4) = u.v;
        }
      // pa: B-frag P^T[k=kv half][n=q], b128 read
      bf16x8 pa[2];
#pragma unroll
      for (int qb = 0; qb < 2; ++qb)
        pa[qb] = *(const bf16x8*)(P + (qb * 16 + li) * 36 + g * 8);
      // O^T += V^T P^T ; l via ones-MFMA (V from LDS, batched b128)
#pragma unroll
      for (int dvf = 0; dvf < 8; ++dvf) {
        int r = dvf * 16 + li;
        int ch = (h * 4 + g) ^ (li & 7);
        bf16x8 vf = *(const bf16x8*)(Vls + r * 64 + ch * 8);
#pragma unroll
        for (int qb = 0; qb < 2; ++qb)
          o[qb][dvf] = __builtin_amdgcn_mfma_f32_16x16x32_bf16(
              vf, pa[qb], o[qb][dvf], 0, 0, 0);
      }
#pragma unroll
      for (int qb = 0; qb < 2; ++qb)
        lacc[qb] = __builtin_amdgcn_mfma_f32_16x16x32_bf16(
            ones, pa[qb], lacc[qb], 0, 0, 0);
    }
    __syncthreads();  // all waves done reading before next stage overwrites
  }

  // partials at WORK index widx: O^T lane layout -> b64 stores
  bf16* op = o_part + (size_t)widx * (128 * 128);
  float* lp = l_part + widx * 128;
#pragma unroll
  for (int qb = 0; qb < 2; ++qb) {
    const int qloc = w * 32 + qb * 16 + li;
    if (g == 0) lp[qloc] = lacc[qb][0];
#pragma unroll
    for (int dvf = 0; dvf < 8; ++dvf) {
      union { bf16 h4[4]; u32x2 v; } u;
#pragma unroll
      for (int j = 0; j < 4; ++j) u.h4[j] = __float2bfloat16(o[qb][dvf][j]);
      *(u32x2*)(op + (size_t)qloc * 128 + dvf * 16 + g * 4) = u.v;
    }
  }
}

// ---------------------------------------------------------------------------
// 4) combine chunk partials: out[row] = sum_c O_c[row] / sum_c l_c[row]
//    q-tile 128: qt = rb>>7; base(qt) = (M+1)(2M + (qt&3)), M=qt>>2;
//    n = (qt+4)>>2 (<=8). partial strides: O 16384, l 128.
// ---------------------------------------------------------------------------
__global__ __launch_bounds__(256) void k_comb(const bf16* __restrict__ op,
                                              const float* __restrict__ lp,
                                              float* __restrict__ out) {
  int i = blockIdx.x * 256 + threadIdx.x;  // 4-col group index, < 524288
  int row = i >> 5;
  int col4 = (i & 31) * 4;
  int b = row >> 12;
  int rb = row & 4095;
  int qt = rb >> 7;
  int lr = rb & 127;
  int M = qt >> 2;
  int base = b * 144 + (M + 1) * (2 * M + (qt & 3));
  int n = (qt + 4) >> 2;
  float l = 0.0f;
  float acc0 = 0, acc1 = 0, acc2 = 0, acc3 = 0;
  for (int c = 0; c < n; ++c) {
    l += lp[(base + c) * 128 + lr];
    union { bf16 h[4]; u32x2 v; } u;
    u.v = *(const u32x2*)(op + (size_t)(base + c) * 16384 + lr * 128 + col4);
    acc0 += __bfloat162float(u.h[0]);
    acc1 += __bfloat162float(u.h[1]);
    acc2 += __bfloat162float(u.h[2]);
    acc3 += __bfloat162float(u.h[3]);
  }
  float linv = 1.0f / l;
  float4 rv;
  rv.x = acc0 * linv; rv.y = acc1 * linv; rv.z = acc2 * linv; rv.w = acc3 * linv;
  ((float4*)out)[i] = rv;
}

// ---------------------------------------------------------------------------
extern "C" void kernel_launch(void* const* d_in, const int* in_sizes, int n_in,
                              void* d_out, int out_size, void* d_ws, size_t ws_size,
                              hipStream_t stream) {
  const float* X  = (const float*)d_in[0];
  const float* Wq = (const float*)d_in[1];
  const float* bq = (const float*)d_in[2];
  const float* Wk = (const float*)d_in[3];
  const float* bk = (const float*)d_in[4];
  const float* Wv = (const float*)d_in[5];
  const float* bv = (const float*)d_in[6];
  float* out = (float*)d_out;

  char* ws = (char*)d_ws;
  // layout (bytes) — fully disjoint, extent 32,538,624 (proven size)
  bf16* Wt  = (bf16*)(ws + 0);              //    786,432
  bf16* Qb  = (bf16*)(ws + 786432);         //  4,194,304
  bf16* Kb  = (bf16*)(ws + 4980736);        //  4,194,304
  bf16* Vt  = (bf16*)(ws + 9175040);        //  4,194,304
  bf16* o_part = (bf16*)(ws + 13369344);    // 18,874,368 (576*128*128*2)
  float* l_part = (float*)(ws + 32243712);  //    294,912

  k_wt<<<dim3(16, 2, 3), dim3(256), 0, stream>>>(Wq, Wk, Wv, Wt);
  k_qkv<<<dim3(256), dim3(512), 0, stream>>>(X, Wt, bq, bk, bv, Qb, Kb, Vt);
  k_attn<<<dim3(576), dim3(256), 0, stream>>>(Qb, Kb, Vt, o_part, l_part);
  k_comb<<<dim3(2048), dim3(256), 0, stream>>>(o_part, l_part, out);
}

// Round 12
// 92.620 us; speedup vs baseline: 1.3229x; 1.0552x over previous
//
#include <hip/hip_runtime.h>
#include <hip/hip_bf16.h>
#include <stdint.h>

// ============================================================================
// Fused causal self-attention block: QKV projection + flash attention.
// bf16 MFMA. No-max softmax (scores bounded; log2e folded into Q scale).
// k_attn = R9's proven v8.1 (dbuf K+V LDS, 49.6us). k_qkv v2: X reg-staged
// with f32->bf16 cast at staging (cast once, not 4x), bf16 X-tile in LDS,
// conflict-free ^((row>>1)&3) swizzle on both X and W fragment reads.
// ============================================================================

typedef __bf16 bf16x8 __attribute__((ext_vector_type(8)));
typedef float  f32x4  __attribute__((ext_vector_type(4)));
typedef unsigned int u32x4 __attribute__((ext_vector_type(4)));
typedef unsigned int u32x2 __attribute__((ext_vector_type(2)));

using bf16 = __hip_bfloat16;

#define AS1 __attribute__((address_space(1)))
#define AS3 __attribute__((address_space(3)))

__device__ __forceinline__ void gl_lds16(const void* g, void* l) {
  __builtin_amdgcn_global_load_lds((AS1 uint32_t*)g, (AS3 uint32_t*)l, 16, 0, 0);
}

// ---------------------------------------------------------------------------
// 1) W [1024][128] fp32 -> Wt[z][128][1024] bf16 (transpose via LDS tile)
// ---------------------------------------------------------------------------
__global__ __launch_bounds__(256) void k_wt(const float* __restrict__ Wq,
                                            const float* __restrict__ Wk,
                                            const float* __restrict__ Wv,
                                            bf16* __restrict__ Wt) {
  __shared__ bf16 t[64][72];
  const float* W = blockIdx.z == 0 ? Wq : (blockIdx.z == 1 ? Wk : Wv);
  int k0 = blockIdx.x * 64, n0 = blockIdx.y * 64;
  int tid = threadIdx.x;
  int r = tid >> 4, c4 = (tid & 15) * 4;
#pragma unroll
  for (int s = 0; s < 4; ++s) {
    int rr = r + s * 16;
    float4 v = *(const float4*)(W + (size_t)(k0 + rr) * 128 + n0 + c4);
    t[rr][c4 + 0] = __float2bfloat16(v.x);
    t[rr][c4 + 1] = __float2bfloat16(v.y);
    t[rr][c4 + 2] = __float2bfloat16(v.z);
    t[rr][c4 + 3] = __float2bfloat16(v.w);
  }
  __syncthreads();
  bf16* out = Wt + (size_t)blockIdx.z * 128 * 1024;
#pragma unroll
  for (int s = 0; s < 4; ++s) {
    int rn = r + s * 16;
    union { bf16 h[4]; u32x2 v; } u;
    u.h[0] = t[c4 + 0][rn]; u.h[1] = t[c4 + 1][rn];
    u.h[2] = t[c4 + 2][rn]; u.h[3] = t[c4 + 3][rn];
    *(u32x2*)(out + (size_t)(n0 + rn) * 1024 + k0 + c4) = u.v;
  }
}

// ---------------------------------------------------------------------------
// 2) fused QKV projection + in-kernel V transpose. v2: X reg-staged with
//    cast-at-staging (bf16 in LDS), conflict-free swizzle ^((row>>1)&3).
//    BM=64, BK=32, 512 thr = 8 waves (2x4), grid 256.
// ---------------------------------------------------------------------------
__global__ __launch_bounds__(512) void k_qkv(const float* __restrict__ X,
                                             const bf16* __restrict__ Wt,
                                             const float* __restrict__ bq,
                                             const float* __restrict__ bk,
                                             const float* __restrict__ bv,
                                             bf16* __restrict__ Qo,
                                             bf16* __restrict__ Ko,
                                             bf16* __restrict__ Vt) {
  __shared__ __align__(16) char smem[57344];
  bf16* Xb = (bf16*)smem;                    // [2][64*32] bf16, 8 KB
  bf16* Ws = (bf16*)(smem + 8192);           // [2][3*128*32] bf16, 48 KB
  bf16* Vs = (bf16*)smem;                    // epilogue: [64][136], 17.4 KB

  const int m0 = blockIdx.x * 64;
  const int tid = threadIdx.x;
  const int lane = tid & 63;
  const int li = lane & 15, g = lane >> 4;
  const int wid = tid >> 6;
  const int wm = wid >> 2, wn = wid & 3;

  // X staging coords: 64 rows x 8 sub-chunks (8B = 4 f32 -> 4 bf16)
  const int xrow = tid >> 3;                    // 0..63
  const int xsc = tid & 7;                      // 0..7
  const int xch = ((xsc >> 1) ^ ((xrow >> 1) & 3)) * 8 + (xsc & 1) * 4;
  // W staging coords (source pre-swizzled, LDS linear)
  const int wr = tid >> 2;                      // 0..127
  const int wc = tid & 3;                       // 16B chunk 0..3

  f32x4 acc[3][2][2] = {};

  // prologue: tile 0
  f32x4 xv = *(const f32x4*)(X + (size_t)(m0 + xrow) * 1024 + xsc * 4);
#pragma unroll
  for (int z = 0; z < 3; ++z)
    gl_lds16(Wt + (size_t)z * 131072 + (size_t)wr * 1024 + (wc ^ ((wr >> 1) & 3)) * 8,
             Ws + z * 4096 + tid * 8);
  {
    union { bf16 h[4]; u32x2 v; } u;
    u.h[0] = __float2bfloat16(xv[0]); u.h[1] = __float2bfloat16(xv[1]);
    u.h[2] = __float2bfloat16(xv[2]); u.h[3] = __float2bfloat16(xv[3]);
    *(u32x2*)(Xb + xrow * 32 + xch) = u.v;
  }

  int cur = 0;
  for (int kt = 0; kt < 32; ++kt) {
    __syncthreads();  // Xb[cur], Ws[cur] ready; prev readers done
    if (kt < 31) {
      const int k0 = (kt + 1) * 32;
      xv = *(const f32x4*)(X + (size_t)(m0 + xrow) * 1024 + k0 + xsc * 4);
#pragma unroll
      for (int z = 0; z < 3; ++z)
        gl_lds16(Wt + (size_t)z * 131072 + (size_t)wr * 1024 + k0 + (wc ^ ((wr >> 1) & 3)) * 8,
                 Ws + (cur ^ 1) * 12288 + z * 4096 + tid * 8);
    }
    // A fragments: clean b128 bf16 reads (conflict-free swizzle)
    bf16x8 af[2];
#pragma unroll
    for (int mf = 0; mf < 2; ++mf) {
      int r = wm * 32 + mf * 16 + li;
      af[mf] = *(const bf16x8*)(Xb + cur * 2048 + r * 32 + ((g ^ ((r >> 1) & 3)) * 8));
    }
#pragma unroll
    for (int z = 0; z < 3; ++z) {
#pragma unroll
      for (int nf = 0; nf < 2; ++nf) {
        int r = wn * 32 + nf * 16 + li;
        bf16x8 bfrag = *(const bf16x8*)(Ws + cur * 12288 + z * 4096 + r * 32 +
                                        ((g ^ ((r >> 1) & 3)) * 8));
#pragma unroll
        for (int mf = 0; mf < 2; ++mf)
          acc[z][mf][nf] = __builtin_amdgcn_mfma_f32_16x16x32_bf16(
              af[mf], bfrag, acc[z][mf][nf], 0, 0, 0);
      }
    }
    // cvt + LDS-write next X tile (load latency hidden under MFMAs above)
    if (kt < 31) {
      union { bf16 h[4]; u32x2 v; } u;
      u.h[0] = __float2bfloat16(xv[0]); u.h[1] = __float2bfloat16(xv[1]);
      u.h[2] = __float2bfloat16(xv[2]); u.h[3] = __float2bfloat16(xv[3]);
      *(u32x2*)(Xb + (cur ^ 1) * 2048 + xrow * 32 + xch) = u.v;
    }
    cur ^= 1;
  }

  // Q, K epilogue (row-major). Q scale = log2(e)/sqrt(128).
#pragma unroll
  for (int z = 0; z < 2; ++z) {
    const float* bias = z == 0 ? bq : bk;
    bf16* Out = z == 0 ? Qo : Ko;
    const float scale = z == 0 ? 0.12752404368678202f : 1.0f;
#pragma unroll
    for (int nf = 0; nf < 2; ++nf) {
      int col = wn * 32 + nf * 16 + li;
      float bb = bias[col];
#pragma unroll
      for (int mf = 0; mf < 2; ++mf)
#pragma unroll
        for (int j = 0; j < 4; ++j) {
          int row = m0 + wm * 32 + mf * 16 + g * 4 + j;
          Out[(size_t)row * 128 + col] =
              __float2bfloat16((acc[z][mf][nf][j] + bb) * scale);
        }
    }
  }

  // V epilogue: bounce through LDS, write transposed Vt [B][128][S].
  __syncthreads();
#pragma unroll
  for (int nf = 0; nf < 2; ++nf) {
    int col = wn * 32 + nf * 16 + li;
    float bb = bv[col];
#pragma unroll
    for (int mf = 0; mf < 2; ++mf)
#pragma unroll
      for (int j = 0; j < 4; ++j) {
        int row = wm * 32 + mf * 16 + g * 4 + j;
        Vs[row * 136 + col] = __float2bfloat16(acc[2][mf][nf][j] + bb);
      }
  }
  __syncthreads();
  const int b = m0 >> 12;
  const int s_off = m0 & 4095;
#pragma unroll
  for (int t2 = 0; t2 < 2; ++t2) {
    int idx = tid + 512 * t2;
    int dv = idx & 127;
    int sg = idx >> 7;
    union { bf16 h[8]; u32x4 v; } u;
#pragma unroll
    for (int si = 0; si < 8; ++si) u.h[si] = Vs[(sg * 8 + si) * 136 + dv];
    *(u32x4*)(Vt + (size_t)(b * 128 + dv) * 4096 + s_off + sg * 8) = u.v;
  }
}

// ---------------------------------------------------------------------------
// 3) causal flash attention — R9's proven v8.1, verbatim. 256 thr = 4 waves x
//    32 q-rows (q-tile 128). K,V dbuf LDS (global_load_lds, XOR-swizzled);
//    P per-wave LDS stride-36, kv-halved. LDS 74,752B -> 2 blocks/CU.
// ---------------------------------------------------------------------------
__global__ __launch_bounds__(256, 2) void k_attn(const bf16* __restrict__ Qb,
                                                 const bf16* __restrict__ Kb,
                                                 const bf16* __restrict__ Vt,
                                                 bf16* __restrict__ o_part,
                                                 float* __restrict__ l_part) {
  __shared__ __align__(16) bf16 Kls[2][64 * 128];  // 32 KB [kv][d] swizzled
  __shared__ __align__(16) bf16 Vls[2][128 * 64];  // 32 KB [dv][kv] swizzled
  __shared__ __align__(16) bf16 Pls[4][32 * 36];   // 9.2 KB per-wave P halves

  const int bid = blockIdx.x;
  const int xcd = bid & 7;
  const int slot = xcd * 72 + (bid >> 3);     // bijective (576 = 8*72)
  const int b = slot / 144;
  const int s = 143 - (slot - b * 144);       // heavy-first work index
  const int widx = b * 144 + s;               // partial-buffer index (k_comb's)
  int qt = 0;
#pragma unroll
  for (int q2 = 1; q2 < 32; ++q2) {
    int M = q2 >> 2;
    if ((M + 1) * (2 * M + (q2 & 3)) <= s) qt = q2;
  }
  const int Mq = qt >> 2;
  const int chunk = s - (Mq + 1) * (2 * Mq + (qt & 3));
  const int ntiles = 2 * qt + 2;
  const int nch = (qt + 4) >> 2;
  const int clen = ntiles / nch;
  const int crem = ntiles - clen * nch;
  const int kt0 = chunk * clen + min(chunk, crem);
  const int kt1 = kt0 + clen + (chunk < crem ? 1 : 0) - 1;

  const int tid = threadIdx.x;
  const int lane = tid & 63;
  const int li = lane & 15, g = lane >> 4;
  const int w = tid >> 6;

  // Q fragments: 32 q-rows/wave via 2 B-frags (q = qt*128 + w*32 + qb*16 + li)
  bf16x8 qf[2][4];
#pragma unroll
  for (int qb = 0; qb < 2; ++qb)
#pragma unroll
    for (int ks = 0; ks < 4; ++ks)
      qf[qb][ks] = *(const bf16x8*)(Qb +
          (size_t)(b * 4096 + qt * 128 + w * 32 + qb * 16 + li) * 128 +
          ks * 32 + g * 8);

  f32x4 o[2][8] = {};
  f32x4 lacc[2] = {};
  bf16x8 ones;
#pragma unroll
  for (int e = 0; e < 8; ++e) ones[e] = (__bf16)1.0f;

  bf16* P = &Pls[w][0];
  const bf16* Vtb = Vt + (size_t)b * 128 * 4096;

  // prologue: stage K+V tile kt0 -> buf 0 (8 gl_lds16/thread)
  {
    const int kv0 = kt0 * 64;
#pragma unroll
    for (int ii = 0; ii < 4; ++ii) {
      int c = tid + 256 * ii;
      int r = c >> 4, cc = c & 15;
      gl_lds16(Kb + (size_t)(b * 4096 + kv0 + r) * 128 + (cc ^ (r & 7)) * 8,
               &Kls[0][c * 8]);
      int r2 = c >> 3, cc2 = c & 7;
      gl_lds16(Vtb + (size_t)r2 * 4096 + kv0 + (cc2 ^ (r2 & 7)) * 8,
               &Vls[0][c * 8]);
    }
  }
  int cur = 0;
  for (int kt = kt0; kt <= kt1; ++kt) {
    __syncthreads();  // buf[cur] staged; all waves done with buf[cur^1]
    if (kt < kt1) {
      const int kv0n = (kt + 1) * 64;
#pragma unroll
      for (int ii = 0; ii < 4; ++ii) {
        int c = tid + 256 * ii;
        int r = c >> 4, cc = c & 15;
        gl_lds16(Kb + (size_t)(b * 4096 + kv0n + r) * 128 + (cc ^ (r & 7)) * 8,
                 &Kls[cur ^ 1][c * 8]);
        int r2 = c >> 3, cc2 = c & 7;
        gl_lds16(Vtb + (size_t)r2 * 4096 + kv0n + (cc2 ^ (r2 & 7)) * 8,
                 &Vls[cur ^ 1][c * 8]);
      }
    }
    const bf16* Kl = &Kls[cur][0];
    const bf16* Vl = &Vls[cur][0];
    const int kv0 = kt * 64;

    // S^T = K Q^T : st[qb][nf][j] = S^T[kv=nf*16+g*4+j][q=w*32+qb*16+li]
    f32x4 st[2][4] = {};
#pragma unroll
    for (int ks = 0; ks < 4; ++ks) {
      bf16x8 kf[4];
#pragma unroll
      for (int nf = 0; nf < 4; ++nf) {
        int r = nf * 16 + li;
        int ch = (ks * 4 + g) ^ (r & 7);
        kf[nf] = *(const bf16x8*)(Kl + r * 128 + ch * 8);
      }
#pragma unroll
      for (int nf = 0; nf < 4; ++nf)
#pragma unroll
        for (int qb = 0; qb < 2; ++qb)
          st[qb][nf] = __builtin_amdgcn_mfma_f32_16x16x32_bf16(
              kf[nf], qf[qb][ks], st[qb][nf], 0, 0, 0);
    }

    if (kt >= 2 * qt) {  // diagonal tiles: causal mask (kv > q)
      const int dk = kv0 - qt * 128;
#pragma unroll
      for (int qb = 0; qb < 2; ++qb) {
        const int qloc = w * 32 + qb * 16 + li;
#pragma unroll
        for (int nf = 0; nf < 4; ++nf)
#pragma unroll
          for (int j = 0; j < 4; ++j)
            if (dk + nf * 16 + g * 4 + j > qloc) st[qb][nf][j] = -1e30f;
      }
    }

    // kv-halved softmax+PV: half h covers kv [h*32, h*32+32)
#pragma unroll
    for (int h = 0; h < 2; ++h) {
      // P = exp2(S) -> b64 stores, P[q'=qb*16+li][c = nfh*16+g*4], stride 36
#pragma unroll
      for (int qb = 0; qb < 2; ++qb)
#pragma unroll
        for (int nfh = 0; nfh < 2; ++nfh) {
          const f32x4 sv = st[qb][h * 2 + nfh];
          union { bf16 h4[4]; u32x2 v; } u;
#pragma unroll
          for (int j = 0; j < 4; ++j)
            u.h4[j] = __float2bfloat16(exp2f(sv[j]));
          *(u32x2*)(P + (qb * 16 + li) * 36 + nfh * 16 + g * 4) = u.v;
        }
      // pa: B-frag P^T[k=kv half][n=q], b128 read
      bf16x8 pa[2];
#pragma unroll
      for (int qb = 0; qb < 2; ++qb)
        pa[qb] = *(const bf16x8*)(P + (qb * 16 + li) * 36 + g * 8);
      // O^T += V^T P^T ; l via ones-MFMA
#pragma unroll
      for (int dvf = 0; dvf < 8; ++dvf) {
        int r = dvf * 16 + li;
        int ch = (h * 4 + g) ^ (li & 7);
        bf16x8 vf = *(const bf16x8*)(Vl + r * 64 + ch * 8);
#pragma unroll
        for (int qb = 0; qb < 2; ++qb)
          o[qb][dvf] = __builtin_amdgcn_mfma_f32_16x16x32_bf16(
              vf, pa[qb], o[qb][dvf], 0, 0, 0);
      }
#pragma unroll
      for (int qb = 0; qb < 2; ++qb)
        lacc[qb] = __builtin_amdgcn_mfma_f32_16x16x32_bf16(
            ones, pa[qb], lacc[qb], 0, 0, 0);
    }
    cur ^= 1;
  }

  // partials at WORK index widx: O^T lane layout -> b64 stores
  bf16* op = o_part + (size_t)widx * (128 * 128);
  float* lp = l_part + widx * 128;
#pragma unroll
  for (int qb = 0; qb < 2; ++qb) {
    const int qloc = w * 32 + qb * 16 + li;
    if (g == 0) lp[qloc] = lacc[qb][0];
#pragma unroll
    for (int dvf = 0; dvf < 8; ++dvf) {
      union { bf16 h4[4]; u32x2 v; } u;
#pragma unroll
      for (int j = 0; j < 4; ++j) u.h4[j] = __float2bfloat16(o[qb][dvf][j]);
      *(u32x2*)(op + (size_t)qloc * 128 + dvf * 16 + g * 4) = u.v;
    }
  }
}

// ---------------------------------------------------------------------------
// 4) combine chunk partials: out[row] = sum_c O_c[row] / sum_c l_c[row]
//    q-tile 128: qt = rb>>7; base(qt) = (M+1)(2M + (qt&3)), M=qt>>2;
//    n = (qt+4)>>2 (<=8). partial strides: O 16384, l 128.
// ---------------------------------------------------------------------------
__global__ __launch_bounds__(256) void k_comb(const bf16* __restrict__ op,
                                              const float* __restrict__ lp,
                                              float* __restrict__ out) {
  int i = blockIdx.x * 256 + threadIdx.x;  // 4-col group index, < 524288
  int row = i >> 5;
  int col4 = (i & 31) * 4;
  int b = row >> 12;
  int rb = row & 4095;
  int qt = rb >> 7;
  int lr = rb & 127;
  int M = qt >> 2;
  int base = b * 144 + (M + 1) * (2 * M + (qt & 3));
  int n = (qt + 4) >> 2;
  float l = 0.0f;
  float acc0 = 0, acc1 = 0, acc2 = 0, acc3 = 0;
  for (int c = 0; c < n; ++c) {
    l += lp[(base + c) * 128 + lr];
    union { bf16 h[4]; u32x2 v; } u;
    u.v = *(const u32x2*)(op + (size_t)(base + c) * 16384 + lr * 128 + col4);
    acc0 += __bfloat162float(u.h[0]);
    acc1 += __bfloat162float(u.h[1]);
    acc2 += __bfloat162float(u.h[2]);
    acc3 += __bfloat162float(u.h[3]);
  }
  float linv = 1.0f / l;
  float4 rv;
  rv.x = acc0 * linv; rv.y = acc1 * linv; rv.z = acc2 * linv; rv.w = acc3 * linv;
  ((float4*)out)[i] = rv;
}

// ---------------------------------------------------------------------------
extern "C" void kernel_launch(void* const* d_in, const int* in_sizes, int n_in,
                              void* d_out, int out_size, void* d_ws, size_t ws_size,
                              hipStream_t stream) {
  const float* X  = (const float*)d_in[0];
  const float* Wq = (const float*)d_in[1];
  const float* bq = (const float*)d_in[2];
  const float* Wk = (const float*)d_in[3];
  const float* bk = (const float*)d_in[4];
  const float* Wv = (const float*)d_in[5];
  const float* bv = (const float*)d_in[6];
  float* out = (float*)d_out;

  char* ws = (char*)d_ws;
  // layout (bytes) — fully disjoint, extent 32,538,624 (proven size)
  bf16* Wt  = (bf16*)(ws + 0);              //    786,432
  bf16* Qb  = (bf16*)(ws + 786432);         //  4,194,304
  bf16* Kb  = (bf16*)(ws + 4980736);        //  4,194,304
  bf16* Vt  = (bf16*)(ws + 9175040);        //  4,194,304
  bf16* o_part = (bf16*)(ws + 13369344);    // 18,874,368 (576*128*128*2)
  float* l_part = (float*)(ws + 32243712);  //    294,912

  k_wt<<<dim3(16, 2, 3), dim3(256), 0, stream>>>(Wq, Wk, Wv, Wt);
  k_qkv<<<dim3(256), dim3(512), 0, stream>>>(X, Wt, bq, bk, bv, Qb, Kb, Vt);
  k_attn<<<dim3(576), dim3(256), 0, stream>>>(Qb, Kb, Vt, o_part, l_part);
  k_comb<<<dim3(2048), dim3(256), 0, stream>>>(o_part, l_part, out);
}

// Round 13
// 87.844 us; speedup vs baseline: 1.3949x; 1.0544x over previous
//
#include <hip/hip_runtime.h>
#include <hip/hip_bf16.h>
#include <stdint.h>

// ============================================================================
// Fused causal self-attention block: QKV projection + flash attention.
// bf16 MFMA. No-max softmax (scores bounded; log2e folded into Q scale).
// k_attn v11: R9's proven schedule (dbuf K+V LDS via global_load_lds,
// XOR-swizzled, one barrier/tile, 576 blocks, chunk<=8) but 512-thr blocks:
// 8 waves x 16 q-rows over the same 128-row q-tile -> 16 waves/CU at the
// same 74.75KB LDS. Per-wave chain halves; partials/k_comb unchanged.
// k_qkv: R9's proven version (f32 X staged via global_load_lds).
// ============================================================================

typedef __bf16 bf16x8 __attribute__((ext_vector_type(8)));
typedef float  f32x4  __attribute__((ext_vector_type(4)));
typedef unsigned int u32x4 __attribute__((ext_vector_type(4)));
typedef unsigned int u32x2 __attribute__((ext_vector_type(2)));

using bf16 = __hip_bfloat16;

#define AS1 __attribute__((address_space(1)))
#define AS3 __attribute__((address_space(3)))

__device__ __forceinline__ void gl_lds16(const void* g, void* l) {
  __builtin_amdgcn_global_load_lds((AS1 uint32_t*)g, (AS3 uint32_t*)l, 16, 0, 0);
}

// ---------------------------------------------------------------------------
// 1) W [1024][128] fp32 -> Wt[z][128][1024] bf16 (transpose via LDS tile)
// ---------------------------------------------------------------------------
__global__ __launch_bounds__(256) void k_wt(const float* __restrict__ Wq,
                                            const float* __restrict__ Wk,
                                            const float* __restrict__ Wv,
                                            bf16* __restrict__ Wt) {
  __shared__ bf16 t[64][72];
  const float* W = blockIdx.z == 0 ? Wq : (blockIdx.z == 1 ? Wk : Wv);
  int k0 = blockIdx.x * 64, n0 = blockIdx.y * 64;
  int tid = threadIdx.x;
  int r = tid >> 4, c4 = (tid & 15) * 4;
#pragma unroll
  for (int s = 0; s < 4; ++s) {
    int rr = r + s * 16;
    float4 v = *(const float4*)(W + (size_t)(k0 + rr) * 128 + n0 + c4);
    t[rr][c4 + 0] = __float2bfloat16(v.x);
    t[rr][c4 + 1] = __float2bfloat16(v.y);
    t[rr][c4 + 2] = __float2bfloat16(v.z);
    t[rr][c4 + 3] = __float2bfloat16(v.w);
  }
  __syncthreads();
  bf16* out = Wt + (size_t)blockIdx.z * 128 * 1024;
#pragma unroll
  for (int s = 0; s < 4; ++s) {
    int rn = r + s * 16;
    union { bf16 h[4]; u32x2 v; } u;
    u.h[0] = t[c4 + 0][rn]; u.h[1] = t[c4 + 1][rn];
    u.h[2] = t[c4 + 2][rn]; u.h[3] = t[c4 + 3][rn];
    *(u32x2*)(out + (size_t)(n0 + rn) * 1024 + k0 + c4) = u.v;
  }
}

// ---------------------------------------------------------------------------
// 2) fused QKV projection + in-kernel V transpose (R9's proven version)
// ---------------------------------------------------------------------------
__global__ __launch_bounds__(512) void k_qkv(const float* __restrict__ X,
                                             const bf16* __restrict__ Wt,
                                             const float* __restrict__ bq,
                                             const float* __restrict__ bk,
                                             const float* __restrict__ bv,
                                             bf16* __restrict__ Qo,
                                             bf16* __restrict__ Ko,
                                             bf16* __restrict__ Vt) {
  __shared__ __align__(16) char smem[65536];
  float* Xs = (float*)smem;                  // [2][64*32] f32, 16 KB
  bf16* Ws = (bf16*)(smem + 16384);          // [2][3*128*32] bf16, 48 KB
  bf16* Vs = (bf16*)smem;                    // epilogue: [64][136], 17.4 KB

  const int m0 = blockIdx.x * 64;
  const int tid = threadIdx.x;
  const int lane = tid & 63;
  const int li = lane & 15, g = lane >> 4;
  const int wid = tid >> 6;
  const int wm = wid >> 2, wn = wid & 3;

  const int xr = tid >> 3;
  const int xc32 = (tid & 7) >> 1;
  const int xhf = tid & 1;
  const int wr = tid >> 2;
  const int wc = tid & 3;

  f32x4 acc[3][2][2] = {};

  {
    gl_lds16(X + (size_t)(m0 + xr) * 1024 + (xc32 ^ (xr & 3)) * 8 + xhf * 4,
             Xs + tid * 4);
#pragma unroll
    for (int z = 0; z < 3; ++z)
      gl_lds16(Wt + (size_t)z * 131072 + (size_t)wr * 1024 + (wc ^ (wr & 3)) * 8,
               Ws + z * 4096 + tid * 8);
  }
  int cur = 0;
  for (int kt = 0; kt < 32; ++kt) {
    __syncthreads();
    if (kt < 31) {
      const int k0 = (kt + 1) * 32;
      gl_lds16(X + (size_t)(m0 + xr) * 1024 + k0 + (xc32 ^ (xr & 3)) * 8 + xhf * 4,
               Xs + (cur ^ 1) * 2048 + tid * 4);
#pragma unroll
      for (int z = 0; z < 3; ++z)
        gl_lds16(Wt + (size_t)z * 131072 + (size_t)wr * 1024 + k0 + (wc ^ (wr & 3)) * 8,
                 Ws + (cur ^ 1) * 12288 + z * 4096 + tid * 8);
    }
    bf16x8 af[2];
#pragma unroll
    for (int mf = 0; mf < 2; ++mf) {
      int r = wm * 32 + mf * 16 + li;
      const float* xp = Xs + cur * 2048 + r * 32 + ((g ^ (r & 3)) * 8);
      f32x4 x0 = *(const f32x4*)xp;
      f32x4 x1 = *(const f32x4*)(xp + 4);
      union { bf16 h[8]; bf16x8 v; } u;
      u.h[0] = __float2bfloat16(x0[0]); u.h[1] = __float2bfloat16(x0[1]);
      u.h[2] = __float2bfloat16(x0[2]); u.h[3] = __float2bfloat16(x0[3]);
      u.h[4] = __float2bfloat16(x1[0]); u.h[5] = __float2bfloat16(x1[1]);
      u.h[6] = __float2bfloat16(x1[2]); u.h[7] = __float2bfloat16(x1[3]);
      af[mf] = u.v;
    }
#pragma unroll
    for (int z = 0; z < 3; ++z) {
#pragma unroll
      for (int nf = 0; nf < 2; ++nf) {
        int r = wn * 32 + nf * 16 + li;
        bf16x8 bfrag =
            *(const bf16x8*)(Ws + cur * 12288 + z * 4096 + r * 32 + ((g ^ (r & 3)) * 8));
#pragma unroll
        for (int mf = 0; mf < 2; ++mf)
          acc[z][mf][nf] = __builtin_amdgcn_mfma_f32_16x16x32_bf16(
              af[mf], bfrag, acc[z][mf][nf], 0, 0, 0);
      }
    }
    cur ^= 1;
  }

#pragma unroll
  for (int z = 0; z < 2; ++z) {
    const float* bias = z == 0 ? bq : bk;
    bf16* Out = z == 0 ? Qo : Ko;
    const float scale = z == 0 ? 0.12752404368678202f : 1.0f;
#pragma unroll
    for (int nf = 0; nf < 2; ++nf) {
      int col = wn * 32 + nf * 16 + li;
      float bb = bias[col];
#pragma unroll
      for (int mf = 0; mf < 2; ++mf)
#pragma unroll
        for (int j = 0; j < 4; ++j) {
          int row = m0 + wm * 32 + mf * 16 + g * 4 + j;
          Out[(size_t)row * 128 + col] =
              __float2bfloat16((acc[z][mf][nf][j] + bb) * scale);
        }
    }
  }

  __syncthreads();
#pragma unroll
  for (int nf = 0; nf < 2; ++nf) {
    int col = wn * 32 + nf * 16 + li;
    float bb = bv[col];
#pragma unroll
    for (int mf = 0; mf < 2; ++mf)
#pragma unroll
      for (int j = 0; j < 4; ++j) {
        int row = wm * 32 + mf * 16 + g * 4 + j;
        Vs[row * 136 + col] = __float2bfloat16(acc[2][mf][nf][j] + bb);
      }
  }
  __syncthreads();
  const int b = m0 >> 12;
  const int s_off = m0 & 4095;
#pragma unroll
  for (int t2 = 0; t2 < 2; ++t2) {
    int idx = tid + 512 * t2;
    int dv = idx & 127;
    int sg = idx >> 7;
    union { bf16 h[8]; u32x4 v; } u;
#pragma unroll
    for (int si = 0; si < 8; ++si) u.h[si] = Vs[(sg * 8 + si) * 136 + dv];
    *(u32x4*)(Vt + (size_t)(b * 128 + dv) * 4096 + s_off + sg * 8) = u.v;
  }
}

// ---------------------------------------------------------------------------
// 3) causal flash attention v11. 512 thr = 8 waves x 16 q-rows (q-tile 128).
//    Same R9 schedule: kv tiles = 2(qt+1), chunks <=8, 144 blocks/batch,
//    grid 576, dbuf K+V, one barrier/tile. LDS 74,752B -> 2 blocks/CU
//    = 16 waves/CU. P per-wave [16][36].
// ---------------------------------------------------------------------------
__global__ __launch_bounds__(512, 4) void k_attn(const bf16* __restrict__ Qb,
                                                 const bf16* __restrict__ Kb,
                                                 const bf16* __restrict__ Vt,
                                                 bf16* __restrict__ o_part,
                                                 float* __restrict__ l_part) {
  __shared__ __align__(16) bf16 Kls[2][64 * 128];  // 32 KB [kv][d] swizzled
  __shared__ __align__(16) bf16 Vls[2][128 * 64];  // 32 KB [dv][kv] swizzled
  __shared__ __align__(16) bf16 Pls[8][16 * 36];   // 9.2 KB per-wave P halves

  const int bid = blockIdx.x;
  const int xcd = bid & 7;
  const int slot = xcd * 72 + (bid >> 3);     // bijective (576 = 8*72)
  const int b = slot / 144;
  const int s = 143 - (slot - b * 144);       // heavy-first work index
  const int widx = b * 144 + s;               // partial-buffer index (k_comb's)
  int qt = 0;
#pragma unroll
  for (int q2 = 1; q2 < 32; ++q2) {
    int M = q2 >> 2;
    if ((M + 1) * (2 * M + (q2 & 3)) <= s) qt = q2;
  }
  const int Mq = qt >> 2;
  const int chunk = s - (Mq + 1) * (2 * Mq + (qt & 3));
  const int ntiles = 2 * qt + 2;
  const int nch = (qt + 4) >> 2;
  const int clen = ntiles / nch;
  const int crem = ntiles - clen * nch;
  const int kt0 = chunk * clen + min(chunk, crem);
  const int kt1 = kt0 + clen + (chunk < crem ? 1 : 0) - 1;

  const int tid = threadIdx.x;
  const int lane = tid & 63;
  const int li = lane & 15, g = lane >> 4;
  const int w8 = tid >> 6;                    // wave id 0..7, owns 16 q-rows

  // Q fragments: 16 q-rows/wave (q = qt*128 + w8*16 + li)
  bf16x8 qf[4];
#pragma unroll
  for (int ks = 0; ks < 4; ++ks)
    qf[ks] = *(const bf16x8*)(Qb +
        (size_t)(b * 4096 + qt * 128 + w8 * 16 + li) * 128 + ks * 32 + g * 8);

  f32x4 o[8] = {};
  f32x4 lacc = {};
  bf16x8 ones;
#pragma unroll
  for (int e = 0; e < 8; ++e) ones[e] = (__bf16)1.0f;

  bf16* P = &Pls[w8][0];
  const bf16* Vtb = Vt + (size_t)b * 128 * 4096;

  // prologue: stage K+V tile kt0 -> buf 0 (4 gl_lds16/thread at 512 thr)
  {
    const int kv0 = kt0 * 64;
#pragma unroll
    for (int ii = 0; ii < 2; ++ii) {
      int c = tid + 512 * ii;
      int r = c >> 4, cc = c & 15;
      gl_lds16(Kb + (size_t)(b * 4096 + kv0 + r) * 128 + (cc ^ (r & 7)) * 8,
               &Kls[0][c * 8]);
      int r2 = c >> 3, cc2 = c & 7;
      gl_lds16(Vtb + (size_t)r2 * 4096 + kv0 + (cc2 ^ (r2 & 7)) * 8,
               &Vls[0][c * 8]);
    }
  }
  int cur = 0;
  for (int kt = kt0; kt <= kt1; ++kt) {
    __syncthreads();  // buf[cur] staged; all waves done with buf[cur^1]
    if (kt < kt1) {
      const int kv0n = (kt + 1) * 64;
#pragma unroll
      for (int ii = 0; ii < 2; ++ii) {
        int c = tid + 512 * ii;
        int r = c >> 4, cc = c & 15;
        gl_lds16(Kb + (size_t)(b * 4096 + kv0n + r) * 128 + (cc ^ (r & 7)) * 8,
                 &Kls[cur ^ 1][c * 8]);
        int r2 = c >> 3, cc2 = c & 7;
        gl_lds16(Vtb + (size_t)r2 * 4096 + kv0n + (cc2 ^ (r2 & 7)) * 8,
                 &Vls[cur ^ 1][c * 8]);
      }
    }
    const bf16* Kl = &Kls[cur][0];
    const bf16* Vl = &Vls[cur][0];
    const int kv0 = kt * 64;

    // S^T = K Q^T : st[nf][j] = S^T[kv=nf*16+g*4+j][q=w8*16+li]
    f32x4 st[4] = {};
#pragma unroll
    for (int ks = 0; ks < 4; ++ks) {
      bf16x8 kf[4];
#pragma unroll
      for (int nf = 0; nf < 4; ++nf) {
        int r = nf * 16 + li;
        int ch = (ks * 4 + g) ^ (r & 7);
        kf[nf] = *(const bf16x8*)(Kl + r * 128 + ch * 8);
      }
#pragma unroll
      for (int nf = 0; nf < 4; ++nf)
        st[nf] = __builtin_amdgcn_mfma_f32_16x16x32_bf16(
            kf[nf], qf[ks], st[nf], 0, 0, 0);
    }

    if (kt >= 2 * qt) {  // diagonal tiles: causal mask (kv > q)
      const int dk = kv0 - qt * 128;
      const int qloc = w8 * 16 + li;
#pragma unroll
      for (int nf = 0; nf < 4; ++nf)
#pragma unroll
        for (int j = 0; j < 4; ++j)
          if (dk + nf * 16 + g * 4 + j > qloc) st[nf][j] = -1e30f;
    }

    // kv-halved softmax+PV: half h covers kv [h*32, h*32+32)
#pragma unroll
    for (int h = 0; h < 2; ++h) {
      // P = exp2(S) -> b64 stores, P[li][c = nfh*16+g*4], stride 36
#pragma unroll
      for (int nfh = 0; nfh < 2; ++nfh) {
        const f32x4 sv = st[h * 2 + nfh];
        union { bf16 h4[4]; u32x2 v; } u;
#pragma unroll
        for (int j = 0; j < 4; ++j)
          u.h4[j] = __float2bfloat16(exp2f(sv[j]));
        *(u32x2*)(P + li * 36 + nfh * 16 + g * 4) = u.v;
      }
      // pa: B-frag P^T[k=kv half][n=q], b128 read
      bf16x8 pa = *(const bf16x8*)(P + li * 36 + g * 8);
      // O^T += V^T P^T ; l via ones-MFMA
#pragma unroll
      for (int dvf = 0; dvf < 8; ++dvf) {
        int r = dvf * 16 + li;
        int ch = (h * 4 + g) ^ (li & 7);
        bf16x8 vf = *(const bf16x8*)(Vl + r * 64 + ch * 8);
        o[dvf] = __builtin_amdgcn_mfma_f32_16x16x32_bf16(
            vf, pa, o[dvf], 0, 0, 0);
      }
      lacc = __builtin_amdgcn_mfma_f32_16x16x32_bf16(ones, pa, lacc, 0, 0, 0);
    }
    cur ^= 1;
  }

  // partials at WORK index widx: O^T lane layout -> b64 stores
  bf16* op = o_part + (size_t)widx * (128 * 128);
  float* lp = l_part + widx * 128;
  {
    const int qloc = w8 * 16 + li;
    if (g == 0) lp[qloc] = lacc[0];
#pragma unroll
    for (int dvf = 0; dvf < 8; ++dvf) {
      union { bf16 h4[4]; u32x2 v; } u;
#pragma unroll
      for (int j = 0; j < 4; ++j) u.h4[j] = __float2bfloat16(o[dvf][j]);
      *(u32x2*)(op + (size_t)qloc * 128 + dvf * 16 + g * 4) = u.v;
    }
  }
}

// ---------------------------------------------------------------------------
// 4) combine chunk partials: out[row] = sum_c O_c[row] / sum_c l_c[row]
//    (unchanged from R9)
// ---------------------------------------------------------------------------
__global__ __launch_bounds__(256) void k_comb(const bf16* __restrict__ op,
                                              const float* __restrict__ lp,
                                              float* __restrict__ out) {
  int i = blockIdx.x * 256 + threadIdx.x;  // 4-col group index, < 524288
  int row = i >> 5;
  int col4 = (i & 31) * 4;
  int b = row >> 12;
  int rb = row & 4095;
  int qt = rb >> 7;
  int lr = rb & 127;
  int M = qt >> 2;
  int base = b * 144 + (M + 1) * (2 * M + (qt & 3));
  int n = (qt + 4) >> 2;
  float l = 0.0f;
  float acc0 = 0, acc1 = 0, acc2 = 0, acc3 = 0;
  for (int c = 0; c < n; ++c) {
    l += lp[(base + c) * 128 + lr];
    union { bf16 h[4]; u32x2 v; } u;
    u.v = *(const u32x2*)(op + (size_t)(base + c) * 16384 + lr * 128 + col4);
    acc0 += __bfloat162float(u.h[0]);
    acc1 += __bfloat162float(u.h[1]);
    acc2 += __bfloat162float(u.h[2]);
    acc3 += __bfloat162float(u.h[3]);
  }
  float linv = 1.0f / l;
  float4 rv;
  rv.x = acc0 * linv; rv.y = acc1 * linv; rv.z = acc2 * linv; rv.w = acc3 * linv;
  ((float4*)out)[i] = rv;
}

// ---------------------------------------------------------------------------
extern "C" void kernel_launch(void* const* d_in, const int* in_sizes, int n_in,
                              void* d_out, int out_size, void* d_ws, size_t ws_size,
                              hipStream_t stream) {
  const float* X  = (const float*)d_in[0];
  const float* Wq = (const float*)d_in[1];
  const float* bq = (const float*)d_in[2];
  const float* Wk = (const float*)d_in[3];
  const float* bk = (const float*)d_in[4];
  const float* Wv = (const float*)d_in[5];
  const float* bv = (const float*)d_in[6];
  float* out = (float*)d_out;

  char* ws = (char*)d_ws;
  // layout (bytes) — fully disjoint, extent 32,538,624 (proven size)
  bf16* Wt  = (bf16*)(ws + 0);              //    786,432
  bf16* Qb  = (bf16*)(ws + 786432);         //  4,194,304
  bf16* Kb  = (bf16*)(ws + 4980736);        //  4,194,304
  bf16* Vt  = (bf16*)(ws + 9175040);        //  4,194,304
  bf16* o_part = (bf16*)(ws + 13369344);    // 18,874,368 (576*128*128*2)
  float* l_part = (float*)(ws + 32243712);  //    294,912

  k_wt<<<dim3(16, 2, 3), dim3(256), 0, stream>>>(Wq, Wk, Wv, Wt);
  k_qkv<<<dim3(256), dim3(512), 0, stream>>>(X, Wt, bq, bk, bv, Qb, Kb, Vt);
  k_attn<<<dim3(576), dim3(512), 0, stream>>>(Qb, Kb, Vt, o_part, l_part);
  k_comb<<<dim3(2048), dim3(256), 0, stream>>>(o_part, l_part, out);
}